// Round 5
// baseline (167.030 us; speedup 1.0000x reference)
//
#include <hip/hip_runtime.h>
#include <hip/hip_bf16.h>
#include <stdint.h>

typedef float f4 __attribute__((ext_vector_type(4)));
typedef float f32x16 __attribute__((ext_vector_type(16)));
typedef short bf16x8 __attribute__((ext_vector_type(8)));

static constexpr int Bc = 16, Nc = 16384, DIN = 64, DOUT = 128, Mc = 4096, KNN = 16;
static constexpr long Rr = (long)Bc * Nc;        // 262144 rows
static constexpr float EPS = 1e-5f;
static constexpr int POS_OUT = Bc * Mc * 3;      // 196608 floats of pos_ds
static constexpr int GBLK = 1024;                // k_gram blocks (256 rows each)
static constexpr int PSTRIDE = 4160;             // 64 colsum + 4096 gram per partial

__device__ __forceinline__ uint32_t cvt2(float a, float b) {
    union { __hip_bfloat162 h; uint32_t u; } c;
    c.h = __float22bfloat162_rn(make_float2(a, b));   // v_cvt_pk_bf16_f32
    return c.u;
}
__device__ __forceinline__ bf16x8 mkfrag(f4 x0, f4 x1) {
    union { uint32_t u[4]; bf16x8 v; } r;
    r.u[0] = cvt2(x0[0], x0[1]);
    r.u[1] = cvt2(x0[2], x0[3]);
    r.u[2] = cvt2(x1[0], x1[1]);
    r.u[3] = cvt2(x1[2], x1[3]);
    return r.v;
}

// ---------------------------------------------------------------------------
// Kernel A: Gram + colsum partials (one 4160-float slice per block) AND
// feat16 (bf16 copy of feat) emitted during staging. 8x8 register tile per
// lane (FMA:DS = 16:1 -- the 4x4 version was ds_read-throughput-bound).
// 1024 blocks x 256 rows; 4 wave-groups each own rows r%4==g; group partials
// merged in-block through LDS.
// ---------------------------------------------------------------------------
__global__ __launch_bounds__(256) void k_gram(const float* __restrict__ feat,
                                              unsigned short* __restrict__ feat16,
                                              float* __restrict__ part)
{
    __shared__ float tile[128 * 64];             // 32 KB; reused as 2x4096 merge buf
    f4* tile4 = (f4*)tile;
    const f4* feat4 = (const f4*)feat;
    const int t = threadIdx.x;
    const long R0 = (long)blockIdx.x * 256;
    const int g = t >> 6;                        // wave group 0..3
    const int lane = t & 63;
    const int i0 = (lane >> 3) << 3;             // 8x8 output tile
    const int j0 = (lane & 7) << 3;
    f4 acc[8][2];
#pragma unroll
    for (int ii = 0; ii < 8; ++ii) { acc[ii][0] = (f4){0,0,0,0}; acc[ii][1] = (f4){0,0,0,0}; }
    f4 csum = (f4){0,0,0,0};

    for (int ch = 0; ch < 2; ++ch) {
        f4 v[8];
#pragma unroll
        for (int i = 0; i < 8; ++i)
            v[i] = feat4[(R0 + ch * 128) * 16 + t + i * 256];   // coalesced
        __syncthreads();                         // prev chunk readers done
#pragma unroll
        for (int i = 0; i < 8; ++i) {
            tile4[t + i * 256] = v[i];
            csum += v[i];                        // col group t&15 fixed per thread
            int idx = t + i * 256;
            int row = idx >> 4, c4 = idx & 15;
            uint2 pk = {cvt2(v[i][0], v[i][1]), cvt2(v[i][2], v[i][3])};
            *(uint2*)(feat16 + (size_t)(R0 + ch * 128 + row) * 64 + c4 * 4) = pk;
        }
        __syncthreads();
#pragma unroll 2
        for (int rr = 0; rr < 32; ++rr) {
            int r = g + rr * 4;                  // this group's rows
            f4 fi0 = tile4[r * 16 + (i0 >> 2)];  // 2-way bank alias: free
            f4 fi1 = tile4[r * 16 + (i0 >> 2) + 1];
            f4 fj0 = tile4[r * 16 + (j0 >> 2)];
            f4 fj1 = tile4[r * 16 + (j0 >> 2) + 1];
#pragma unroll
            for (int ii = 0; ii < 4; ++ii) {
                acc[ii][0] += fi0[ii] * fj0;
                acc[ii][1] += fi0[ii] * fj1;
                acc[ii + 4][0] += fi1[ii] * fj0;
                acc[ii + 4][1] += fi1[ii] * fj1;
            }
        }
    }

    float* pb = part + (size_t)blockIdx.x * PSTRIDE;
    __syncthreads();
    tile4[t] = csum;                             // colsum reduce
    __syncthreads();
    if (t < 16) {
        f4 s = (f4){0,0,0,0};
#pragma unroll
        for (int q = 0; q < 16; ++q) s += tile4[q * 16 + t];
        ((f4*)pb)[t] = s;
    }
    __syncthreads();
    // merge 4 group-accs -> one 4096 partial: g0+g2 -> buf0, g1+g3 -> buf1
    float* buf = tile + (g & 1) * 4096;
    if (g < 2) {
#pragma unroll
        for (int ii = 0; ii < 8; ++ii) {
            *(f4*)(buf + (i0 + ii) * 64 + j0) = acc[ii][0];
            *(f4*)(buf + (i0 + ii) * 64 + j0 + 4) = acc[ii][1];
        }
    }
    __syncthreads();
    if (g >= 2) {
#pragma unroll
        for (int ii = 0; ii < 8; ++ii) {
            f4* d = (f4*)(buf + (i0 + ii) * 64 + j0);
            d[0] += acc[ii][0];
            d[1] += acc[ii][1];
        }
    }
    __syncthreads();
#pragma unroll
    for (int q = 0; q < 16; ++q) {
        int e = t + q * 256;
        pb[64 + e] = tile[e] + tile[4096 + e];
    }
}

// ---------------------------------------------------------------------------
// Kernel A2: reduce GBLK partials -> stats[4160].
// ---------------------------------------------------------------------------
__global__ __launch_bounds__(256) void k_reduce(const float* __restrict__ part,
                                                float* __restrict__ stats)
{
    const int gid = blockIdx.x * 256 + threadIdx.x;
    if (gid >= PSTRIDE) return;
    float s0 = 0.f, s1 = 0.f, s2 = 0.f, s3 = 0.f;
    for (int p = 0; p < GBLK; p += 4) {
        s0 += part[(size_t)p * PSTRIDE + gid];
        s1 += part[(size_t)(p + 1) * PSTRIDE + gid];
        s2 += part[(size_t)(p + 2) * PSTRIDE + gid];
        s3 += part[(size_t)(p + 3) * PSTRIDE + gid];
    }
    stats[gid] = (s0 + s1) + (s2 + s3);
}

// ---------------------------------------------------------------------------
// Fallback Gram (atomic) for tiny ws.
// ---------------------------------------------------------------------------
__global__ __launch_bounds__(256) void k_gram_at(const float* __restrict__ feat,
                                                 float* __restrict__ stats)
{
    __shared__ float tile[64 * 64];
    f4* tile4 = (f4*)tile;
    const f4* feat4 = (const f4*)feat;
    const int t = threadIdx.x;
    const int i0 = (t >> 4) << 2;
    const int j0 = (t & 15) << 2;
    float acc[16];
#pragma unroll
    for (int k = 0; k < 16; ++k) acc[k] = 0.f;
    float csum = 0.f;
    for (int c = 0; c < 8; ++c) {
        const int base4 = (blockIdx.x * 512 + c * 64) * 16;
        __syncthreads();
#pragma unroll
        for (int k = 0; k < 4; ++k) tile4[t + k * 256] = feat4[base4 + t + k * 256];
        __syncthreads();
        for (int r = 0; r < 64; ++r) {
            f4 fi = tile4[r * 16 + (i0 >> 2)];
            f4 fj = tile4[r * 16 + (j0 >> 2)];
#pragma unroll
            for (int ii = 0; ii < 4; ++ii)
#pragma unroll
                for (int jj = 0; jj < 4; ++jj)
                    acc[ii * 4 + jj] = fmaf(fi[ii], fj[jj], acc[ii * 4 + jj]);
        }
        if (t < 64) {
            for (int r = 0; r < 64; ++r) csum += tile[r * 64 + t];
        }
    }
#pragma unroll
    for (int ii = 0; ii < 4; ++ii)
#pragma unroll
        for (int jj = 0; jj < 4; ++jj)
            atomicAdd(&stats[64 + (i0 + ii) * 64 + (j0 + jj)], acc[ii * 4 + jj]);
    if (t < 64) atomicAdd(&stats[t], csum);
}

// ---------------------------------------------------------------------------
// Kernel B: per-channel BN scale/shift from Gram + colsum (bias b cancels).
// ---------------------------------------------------------------------------
__global__ __launch_bounds__(64) void k_stats(const float* __restrict__ stats,
                                              const float* __restrict__ W,
                                              const float* __restrict__ gamma,
                                              const float* __restrict__ beta,
                                              float* __restrict__ ST)
{
    const int o = blockIdx.x;
    const int i = threadIdx.x;
    __shared__ float wrow[64];
    wrow[i] = W[o * 64 + i];
    __syncthreads();
    const float* G = stats + 64;
    float inner = 0.f;
    for (int j = 0; j < 64; ++j) inner = fmaf(G[i * 64 + j], wrow[j], inner);
    float qi = inner * wrow[i];
    float cwi = stats[i] * wrow[i];
#pragma unroll
    for (int off = 32; off > 0; off >>= 1) {
        qi += __shfl_down(qi, off);
        cwi += __shfl_down(cwi, off);
    }
    if (i == 0) {
        const double invR = 1.0 / (double)Rr;
        double meanr = (double)cwi * invR;
        double var = (double)qi * invR - meanr * meanr;
        float s = gamma[o] / sqrtf((float)var + EPS);
        ST[o] = s;
        ST[DOUT + o] = beta[o] - (float)meanr * s;
    }
}

// ---------------------------------------------------------------------------
// Kernel P: pos downsample gather (moved out of the hot kernel).
// ---------------------------------------------------------------------------
__global__ __launch_bounds__(256) void k_pos(const int* __restrict__ fps,
                                             const float* __restrict__ pos,
                                             float* __restrict__ out)
{
    const int tt = blockIdx.x * 256 + threadIdx.x;   // < 196608 exactly
    const int p = tt / 3, d = tt - p * 3;
    const int b = p >> 12;
    const int id = fps[p];
    out[tt] = pos[((size_t)b * Nc + id) * 3 + d];
}

// ---------------------------------------------------------------------------
// Kernel C (fused gather+GEMM+max, 32x32x16): 2 (b,m) pairs per MFMA group.
// A = 32 gathered bf16 feat rows (2 pairs x 16 neighbors; lane m=l&31,
// k=(l>>5)*8+j), B = W fragments held entirely in 64 VGPRs (no LDS, no
// barriers). C layout row=(reg&3)+8*(reg>>2)+4*hi puts 8 of each pair's
// neighbors in-lane: 7 fmax + 1 shfl_xor(32) finishes the 16-way max.
// BN affine+relu after max (valid: s=gamma/sigma>0). kidx preloaded for all
// 4 iterations (no dependent-address stalls); 2-deep gather pipeline.
// feat16 slice per batch = 2 MB; 2 batches/XCD = 4 MB = exact L2 fit.
// ---------------------------------------------------------------------------
__global__ __launch_bounds__(256) void k_gmax(const unsigned short* __restrict__ feat16,
                                              const float* __restrict__ W,
                                              const float* __restrict__ ST,
                                              const int* __restrict__ kidx,
                                              float* __restrict__ out)
{
    const int t = threadIdx.x;
    const int lane = t & 63;
    const int w = t >> 6;
    const int l31 = lane & 31;
    const int hi = lane >> 5;

    // XCD-aware remap: bl%8 = XCD, 2 batches per XCD
    const int bl = blockIdx.x;
    const int j = bl >> 3;
    const int batch = (bl & 7) + 8 * (j >> 7);
    const int p0 = batch * Mc + (j & 127) * 32 + w * 8;

    // W fragments: wf[cg][ks] covers channels cg*32+l31, k = ks*16+hi*8+0..7
    bf16x8 wf[4][4];
    const f4* W4 = (const f4*)W;
#pragma unroll
    for (int cg = 0; cg < 4; ++cg)
#pragma unroll
        for (int ks = 0; ks < 4; ++ks) {
            f4 w0 = W4[(cg * 32 + l31) * 16 + ks * 4 + hi * 2];
            f4 w1 = W4[(cg * 32 + l31) * 16 + ks * 4 + hi * 2 + 1];
            wf[cg][ks] = mkfrag(w0, w1);
        }
    float sc[4], tc[4];
#pragma unroll
    for (int cg = 0; cg < 4; ++cg) {
        sc[cg] = ST[cg * 32 + l31];
        tc[cg] = ST[DOUT + cg * 32 + l31];
    }

    int ids[4];
#pragma unroll
    for (int it = 0; it < 4; ++it)
        ids[it] = kidx[(p0 + 2 * it) * KNN + l31];   // 32 neighbors of 2 pairs

    const unsigned short* fb = feat16 + (size_t)batch * Nc * 64 + hi * 8;

    bf16x8 A[2][4];
#define LOADA(sl_, it_) {                                        \
        const unsigned short* rp = fb + (size_t)ids[it_] * 64;   \
        A[sl_][0] = *(const bf16x8*)(rp);                        \
        A[sl_][1] = *(const bf16x8*)(rp + 16);                   \
        A[sl_][2] = *(const bf16x8*)(rp + 32);                   \
        A[sl_][3] = *(const bf16x8*)(rp + 48); }

    LOADA(0, 0);
#pragma unroll
    for (int it = 0; it < 4; ++it) {
        if (it < 3) LOADA((it + 1) & 1, it + 1);     // prefetch next 2 pairs
        const int sl = it & 1;
        const size_t obase = POS_OUT + (size_t)(p0 + 2 * it + hi) * DOUT + l31;
#pragma unroll
        for (int cg = 0; cg < 4; ++cg) {
            f32x16 acc = {};
#pragma unroll
            for (int ks = 0; ks < 4; ++ks)
                acc = __builtin_amdgcn_mfma_f32_32x32x16_bf16(A[sl][ks], wf[cg][ks], acc, 0, 0, 0);
            float vmA = fmaxf(fmaxf(fmaxf(acc[0], acc[1]), fmaxf(acc[2], acc[3])),
                              fmaxf(fmaxf(acc[4], acc[5]), fmaxf(acc[6], acc[7])));
            float vmB = fmaxf(fmaxf(fmaxf(acc[8], acc[9]), fmaxf(acc[10], acc[11])),
                              fmaxf(fmaxf(acc[12], acc[13]), fmaxf(acc[14], acc[15])));
            vmA = fmaxf(vmA, __shfl_xor(vmA, 32));   // other half's 8 neighbors
            vmB = fmaxf(vmB, __shfl_xor(vmB, 32));
            float vsel = hi ? vmB : vmA;             // lo lanes: pair0, hi: pair1
            out[obase + cg * 32] = fmaxf(fmaf(vsel, sc[cg], tc[cg]), 0.f);
        }
    }
#undef LOADA
}

// ---------------------------------------------------------------------------
// Fallback (ws too small): recompute h at gathered rows (includes pos).
// ---------------------------------------------------------------------------
__global__ __launch_bounds__(128) void k_gather_rc(const float* __restrict__ feat,
                                                   const float* __restrict__ W,
                                                   const float* __restrict__ ST,
                                                   const int* __restrict__ kidx,
                                                   const int* __restrict__ fps,
                                                   const float* __restrict__ pos,
                                                   float* __restrict__ out)
{
    __shared__ float frow[KNN][DIN];
    const int p = blockIdx.x;
    const int o = threadIdx.x;
    const int b = p >> 12;
    const f4* featf = (const f4*)feat;
    f4* frow4 = (f4*)frow;
#pragma unroll
    for (int q = 0; q < 2; ++q) {
        int jj = o + q * 128;
        int row = jj >> 4, i4 = jj & 15;
        int id = kidx[p * KNN + row];
        frow4[jj] = featf[((size_t)b * Nc + id) * 16 + i4];
    }
    __syncthreads();
    float wreg[64];
#pragma unroll
    for (int i4 = 0; i4 < 16; ++i4) {
        f4 wv = ((const f4*)W)[o * 16 + i4];
        wreg[i4 * 4 + 0] = wv[0];
        wreg[i4 * 4 + 1] = wv[1];
        wreg[i4 * 4 + 2] = wv[2];
        wreg[i4 * 4 + 3] = wv[3];
    }
    const float s = ST[o], tt = ST[DOUT + o];
    float vm = 0.f;
    for (int k = 0; k < KNN; ++k) {
        float acc = 0.f;
#pragma unroll
        for (int i = 0; i < 64; ++i) acc = fmaf(frow[k][i], wreg[i], acc);
        vm = fmaxf(vm, fmaf(acc, s, tt));
    }
    out[POS_OUT + (size_t)p * DOUT + o] = vm;
    if (o < 3) {
        int id = fps[p];
        out[p * 3 + o] = pos[((size_t)b * Nc + id) * 3 + o];
    }
}

extern "C" void kernel_launch(void* const* d_in, const int* in_sizes, int n_in,
                              void* d_out, int out_size, void* d_ws, size_t ws_size,
                              hipStream_t stream)
{
    const float* pos   = (const float*)d_in[0];
    const float* feat  = (const float*)d_in[1];
    const int*   fps   = (const int*)d_in[2];
    const int*   kidx  = (const int*)d_in[3];
    const float* W     = (const float*)d_in[4];
    // d_in[5] = bias b: cancels exactly under BatchNorm, unused
    const float* gamma = (const float*)d_in[6];
    const float* beta  = (const float*)d_in[7];
    float* out = (float*)d_out;

    float* stats = (float*)d_ws;                 // [0,4160) colsum+gram
    float* ST = stats + PSTRIDE;                 // s,t (256 floats)
    const size_t F16_OFF = 32768;
    const size_t F16_BYTES = (size_t)Rr * DIN * 2;               // 32 MiB
    unsigned short* feat16 = (unsigned short*)((char*)d_ws + F16_OFF);
    float* part = (float*)((char*)d_ws + F16_OFF + F16_BYTES);   // 17 MB partials
    const size_t need = F16_OFF + F16_BYTES + (size_t)GBLK * PSTRIDE * 4;

    if (ws_size >= need) {
        k_gram<<<GBLK, 256, 0, stream>>>(feat, feat16, part);
        k_reduce<<<(PSTRIDE + 255) / 256, 256, 0, stream>>>(part, stats);
        k_stats<<<DOUT, 64, 0, stream>>>(stats, W, gamma, beta, ST);
        k_pos<<<(POS_OUT + 255) / 256, 256, 0, stream>>>(fps, pos, out);
        k_gmax<<<2048, 256, 0, stream>>>(feat16, W, ST, kidx, out);
    } else {
        hipMemsetAsync(d_ws, 0, PSTRIDE * 4, stream);
        k_gram_at<<<512, 256, 0, stream>>>(feat, stats);
        k_stats<<<DOUT, 64, 0, stream>>>(stats, W, gamma, beta, ST);
        k_gather_rc<<<Bc * Mc, 128, 0, stream>>>(feat, W, ST, kidx, fps, pos, out);
    }
}

// Round 6
// 101.009 us; speedup vs baseline: 1.6536x; 1.6536x over previous
//
#include <hip/hip_runtime.h>
#include <hip/hip_bf16.h>
#include <stdint.h>

typedef float f4 __attribute__((ext_vector_type(4)));
typedef float f32x16 __attribute__((ext_vector_type(16)));
typedef short bf16x8 __attribute__((ext_vector_type(8)));

static constexpr int Bc = 16, Nc = 16384, DIN = 64, DOUT = 128, Mc = 4096, KNN = 16;
static constexpr long Rr = (long)Bc * Nc;        // 262144 rows
static constexpr float EPS = 1e-5f;
static constexpr int POS_OUT = Bc * Mc * 3;      // 196608 floats of pos_ds
static constexpr int GBLK = 1024;                // k_gram blocks (256 rows each)
static constexpr int PSTRIDE = 4160;             // 64 colsum + 4096 gram per partial
static constexpr int RGRP = 32;                  // reduction groups (stage 1)

__device__ __forceinline__ uint32_t cvt2(float a, float b) {
    union { __hip_bfloat162 h; uint32_t u; } c;
    c.h = __float22bfloat162_rn(make_float2(a, b));   // v_cvt_pk_bf16_f32
    return c.u;
}
__device__ __forceinline__ bf16x8 mkfrag(f4 x0, f4 x1) {
    union { uint32_t u[4]; bf16x8 v; } r;
    r.u[0] = cvt2(x0[0], x0[1]);
    r.u[1] = cvt2(x0[2], x0[3]);
    r.u[2] = cvt2(x1[0], x1[1]);
    r.u[3] = cvt2(x1[2], x1[3]);
    return r.v;
}

// ---------------------------------------------------------------------------
// Kernel A: Gram + colsum partials (one 4160-float slice per block) AND
// feat16 (bf16 copy of feat) emitted during staging. 8x8 register tile.
// ---------------------------------------------------------------------------
__global__ __launch_bounds__(256) void k_gram(const float* __restrict__ feat,
                                              unsigned short* __restrict__ feat16,
                                              float* __restrict__ part)
{
    __shared__ float tile[128 * 64];             // 32 KB; reused as 2x4096 merge buf
    f4* tile4 = (f4*)tile;
    const f4* feat4 = (const f4*)feat;
    const int t = threadIdx.x;
    const long R0 = (long)blockIdx.x * 256;
    const int g = t >> 6;                        // wave group 0..3
    const int lane = t & 63;
    const int i0 = (lane >> 3) << 3;             // 8x8 output tile
    const int j0 = (lane & 7) << 3;
    f4 acc[8][2];
#pragma unroll
    for (int ii = 0; ii < 8; ++ii) { acc[ii][0] = (f4){0,0,0,0}; acc[ii][1] = (f4){0,0,0,0}; }
    f4 csum = (f4){0,0,0,0};

    for (int ch = 0; ch < 2; ++ch) {
        f4 v[8];
#pragma unroll
        for (int i = 0; i < 8; ++i)
            v[i] = feat4[(R0 + ch * 128) * 16 + t + i * 256];   // coalesced
        __syncthreads();                         // prev chunk readers done
#pragma unroll
        for (int i = 0; i < 8; ++i) {
            tile4[t + i * 256] = v[i];
            csum += v[i];                        // col group t&15 fixed per thread
            int idx = t + i * 256;
            int row = idx >> 4, c4 = idx & 15;
            uint2 pk = {cvt2(v[i][0], v[i][1]), cvt2(v[i][2], v[i][3])};
            *(uint2*)(feat16 + (size_t)(R0 + ch * 128 + row) * 64 + c4 * 4) = pk;
        }
        __syncthreads();
#pragma unroll 2
        for (int rr = 0; rr < 32; ++rr) {
            int r = g + rr * 4;                  // this group's rows
            f4 fi0 = tile4[r * 16 + (i0 >> 2)];  // 2-way bank alias: free
            f4 fi1 = tile4[r * 16 + (i0 >> 2) + 1];
            f4 fj0 = tile4[r * 16 + (j0 >> 2)];
            f4 fj1 = tile4[r * 16 + (j0 >> 2) + 1];
#pragma unroll
            for (int ii = 0; ii < 4; ++ii) {
                acc[ii][0] += fi0[ii] * fj0;
                acc[ii][1] += fi0[ii] * fj1;
                acc[ii + 4][0] += fi1[ii] * fj0;
                acc[ii + 4][1] += fi1[ii] * fj1;
            }
        }
    }

    float* pb = part + (size_t)blockIdx.x * PSTRIDE;
    __syncthreads();
    tile4[t] = csum;                             // colsum reduce
    __syncthreads();
    if (t < 16) {
        f4 s = (f4){0,0,0,0};
#pragma unroll
        for (int q = 0; q < 16; ++q) s += tile4[q * 16 + t];
        ((f4*)pb)[t] = s;
    }
    __syncthreads();
    // merge 4 group-accs -> one 4096 partial: g0+g2 -> buf0, g1+g3 -> buf1
    float* buf = tile + (g & 1) * 4096;
    if (g < 2) {
#pragma unroll
        for (int ii = 0; ii < 8; ++ii) {
            *(f4*)(buf + (i0 + ii) * 64 + j0) = acc[ii][0];
            *(f4*)(buf + (i0 + ii) * 64 + j0 + 4) = acc[ii][1];
        }
    }
    __syncthreads();
    if (g >= 2) {
#pragma unroll
        for (int ii = 0; ii < 8; ++ii) {
            f4* d = (f4*)(buf + (i0 + ii) * 64 + j0);
            d[0] += acc[ii][0];
            d[1] += acc[ii][1];
        }
    }
    __syncthreads();
#pragma unroll
    for (int q = 0; q < 16; ++q) {
        int e = t + q * 256;
        pb[64 + e] = tile[e] + tile[4096 + e];
    }
}

// ---------------------------------------------------------------------------
// Kernel A2a: stage-1 reduce. GBLK partials -> RGRP group-partials.
// 544 blocks (17 x 32); each thread sums GBLK/RGRP=32 values via 8
// independent chains (~4 exposed latencies). The old single-stage version
// ran 256 serial-latency iterations on 17 blocks: 74 us. This is ~1 us.
// ---------------------------------------------------------------------------
__global__ __launch_bounds__(256) void k_reduce1(const float* __restrict__ part,
                                                 float* __restrict__ part2)
{
    const int gid = blockIdx.x * 256 + threadIdx.x;
    const int grp = blockIdx.y;
    if (gid >= PSTRIDE) return;
    const float* pp = part + (size_t)grp * (GBLK / RGRP) * PSTRIDE + gid;
    float s[8];
#pragma unroll
    for (int j = 0; j < 8; ++j) s[j] = 0.f;
#pragma unroll
    for (int i = 0; i < GBLK / RGRP; i += 8)
#pragma unroll
        for (int j = 0; j < 8; ++j)
            s[j] += pp[(size_t)(i + j) * PSTRIDE];
    part2[(size_t)grp * PSTRIDE + gid] =
        ((s[0] + s[1]) + (s[2] + s[3])) + ((s[4] + s[5]) + (s[6] + s[7]));
}

// ---------------------------------------------------------------------------
// Kernel A2b: stage-2 reduce. RGRP group-partials -> stats[4160]. L2-hot.
// ---------------------------------------------------------------------------
__global__ __launch_bounds__(256) void k_reduce2(const float* __restrict__ part2,
                                                 float* __restrict__ stats)
{
    const int gid = blockIdx.x * 256 + threadIdx.x;
    if (gid >= PSTRIDE) return;
    float s[8];
#pragma unroll
    for (int j = 0; j < 8; ++j) s[j] = 0.f;
#pragma unroll
    for (int i = 0; i < RGRP; i += 8)
#pragma unroll
        for (int j = 0; j < 8; ++j)
            s[j] += part2[(size_t)(i + j) * PSTRIDE + gid];
    stats[gid] = ((s[0] + s[1]) + (s[2] + s[3])) + ((s[4] + s[5]) + (s[6] + s[7]));
}

// ---------------------------------------------------------------------------
// Fallback Gram (atomic) for tiny ws.
// ---------------------------------------------------------------------------
__global__ __launch_bounds__(256) void k_gram_at(const float* __restrict__ feat,
                                                 float* __restrict__ stats)
{
    __shared__ float tile[64 * 64];
    f4* tile4 = (f4*)tile;
    const f4* feat4 = (const f4*)feat;
    const int t = threadIdx.x;
    const int i0 = (t >> 4) << 2;
    const int j0 = (t & 15) << 2;
    float acc[16];
#pragma unroll
    for (int k = 0; k < 16; ++k) acc[k] = 0.f;
    float csum = 0.f;
    for (int c = 0; c < 8; ++c) {
        const int base4 = (blockIdx.x * 512 + c * 64) * 16;
        __syncthreads();
#pragma unroll
        for (int k = 0; k < 4; ++k) tile4[t + k * 256] = feat4[base4 + t + k * 256];
        __syncthreads();
        for (int r = 0; r < 64; ++r) {
            f4 fi = tile4[r * 16 + (i0 >> 2)];
            f4 fj = tile4[r * 16 + (j0 >> 2)];
#pragma unroll
            for (int ii = 0; ii < 4; ++ii)
#pragma unroll
                for (int jj = 0; jj < 4; ++jj)
                    acc[ii * 4 + jj] = fmaf(fi[ii], fj[jj], acc[ii * 4 + jj]);
        }
        if (t < 64) {
            for (int r = 0; r < 64; ++r) csum += tile[r * 64 + t];
        }
    }
#pragma unroll
    for (int ii = 0; ii < 4; ++ii)
#pragma unroll
        for (int jj = 0; jj < 4; ++jj)
            atomicAdd(&stats[64 + (i0 + ii) * 64 + (j0 + jj)], acc[ii * 4 + jj]);
    if (t < 64) atomicAdd(&stats[t], csum);
}

// ---------------------------------------------------------------------------
// Kernel B: per-channel BN scale/shift from Gram + colsum (bias b cancels).
// ---------------------------------------------------------------------------
__global__ __launch_bounds__(64) void k_stats(const float* __restrict__ stats,
                                              const float* __restrict__ W,
                                              const float* __restrict__ gamma,
                                              const float* __restrict__ beta,
                                              float* __restrict__ ST)
{
    const int o = blockIdx.x;
    const int i = threadIdx.x;
    __shared__ float wrow[64];
    wrow[i] = W[o * 64 + i];
    __syncthreads();
    const float* G = stats + 64;
    float inner = 0.f;
    for (int j = 0; j < 64; ++j) inner = fmaf(G[i * 64 + j], wrow[j], inner);
    float qi = inner * wrow[i];
    float cwi = stats[i] * wrow[i];
#pragma unroll
    for (int off = 32; off > 0; off >>= 1) {
        qi += __shfl_down(qi, off);
        cwi += __shfl_down(cwi, off);
    }
    if (i == 0) {
        const double invR = 1.0 / (double)Rr;
        double meanr = (double)cwi * invR;
        double var = (double)qi * invR - meanr * meanr;
        float s = gamma[o] / sqrtf((float)var + EPS);
        ST[o] = s;
        ST[DOUT + o] = beta[o] - (float)meanr * s;
    }
}

// ---------------------------------------------------------------------------
// Kernel P: pos downsample gather.
// ---------------------------------------------------------------------------
__global__ __launch_bounds__(256) void k_pos(const int* __restrict__ fps,
                                             const float* __restrict__ pos,
                                             float* __restrict__ out)
{
    const int tt = blockIdx.x * 256 + threadIdx.x;   // < 196608 exactly
    const int p = tt / 3, d = tt - p * 3;
    const int b = p >> 12;
    const int id = fps[p];
    out[tt] = pos[((size_t)b * Nc + id) * 3 + d];
}

// ---------------------------------------------------------------------------
// Kernel C (fused gather+GEMM+max, 32x32x16): 2 (b,m) pairs per MFMA group.
// W fragments in VGPRs (no LDS/barriers); max over neighbors in C-layout;
// BN affine+relu after max (valid: s>0); kidx preloaded; 2-deep pipeline;
// XCD-aware remap (2 batches -> one XCD's L2, 4 MB slice).
// ---------------------------------------------------------------------------
__global__ __launch_bounds__(256) void k_gmax(const unsigned short* __restrict__ feat16,
                                              const float* __restrict__ W,
                                              const float* __restrict__ ST,
                                              const int* __restrict__ kidx,
                                              float* __restrict__ out)
{
    const int t = threadIdx.x;
    const int lane = t & 63;
    const int w = t >> 6;
    const int l31 = lane & 31;
    const int hi = lane >> 5;

    const int bl = blockIdx.x;
    const int j = bl >> 3;
    const int batch = (bl & 7) + 8 * (j >> 7);
    const int p0 = batch * Mc + (j & 127) * 32 + w * 8;

    bf16x8 wf[4][4];
    const f4* W4 = (const f4*)W;
#pragma unroll
    for (int cg = 0; cg < 4; ++cg)
#pragma unroll
        for (int ks = 0; ks < 4; ++ks) {
            f4 w0 = W4[(cg * 32 + l31) * 16 + ks * 4 + hi * 2];
            f4 w1 = W4[(cg * 32 + l31) * 16 + ks * 4 + hi * 2 + 1];
            wf[cg][ks] = mkfrag(w0, w1);
        }
    float sc[4], tc[4];
#pragma unroll
    for (int cg = 0; cg < 4; ++cg) {
        sc[cg] = ST[cg * 32 + l31];
        tc[cg] = ST[DOUT + cg * 32 + l31];
    }

    int ids[4];
#pragma unroll
    for (int it = 0; it < 4; ++it)
        ids[it] = kidx[(p0 + 2 * it) * KNN + l31];

    const unsigned short* fb = feat16 + (size_t)batch * Nc * 64 + hi * 8;

    bf16x8 A[2][4];
#define LOADA(sl_, it_) {                                        \
        const unsigned short* rp = fb + (size_t)ids[it_] * 64;   \
        A[sl_][0] = *(const bf16x8*)(rp);                        \
        A[sl_][1] = *(const bf16x8*)(rp + 16);                   \
        A[sl_][2] = *(const bf16x8*)(rp + 32);                   \
        A[sl_][3] = *(const bf16x8*)(rp + 48); }

    LOADA(0, 0);
#pragma unroll
    for (int it = 0; it < 4; ++it) {
        if (it < 3) LOADA((it + 1) & 1, it + 1);
        const int sl = it & 1;
        const size_t obase = POS_OUT + (size_t)(p0 + 2 * it + hi) * DOUT + l31;
#pragma unroll
        for (int cg = 0; cg < 4; ++cg) {
            f32x16 acc = {};
#pragma unroll
            for (int ks = 0; ks < 4; ++ks)
                acc = __builtin_amdgcn_mfma_f32_32x32x16_bf16(A[sl][ks], wf[cg][ks], acc, 0, 0, 0);
            float vmA = fmaxf(fmaxf(fmaxf(acc[0], acc[1]), fmaxf(acc[2], acc[3])),
                              fmaxf(fmaxf(acc[4], acc[5]), fmaxf(acc[6], acc[7])));
            float vmB = fmaxf(fmaxf(fmaxf(acc[8], acc[9]), fmaxf(acc[10], acc[11])),
                              fmaxf(fmaxf(acc[12], acc[13]), fmaxf(acc[14], acc[15])));
            vmA = fmaxf(vmA, __shfl_xor(vmA, 32));
            vmB = fmaxf(vmB, __shfl_xor(vmB, 32));
            float vsel = hi ? vmB : vmA;
            out[obase + cg * 32] = fmaxf(fmaf(vsel, sc[cg], tc[cg]), 0.f);
        }
    }
#undef LOADA
}

// ---------------------------------------------------------------------------
// Fallback (ws too small): recompute h at gathered rows (includes pos).
// ---------------------------------------------------------------------------
__global__ __launch_bounds__(128) void k_gather_rc(const float* __restrict__ feat,
                                                   const float* __restrict__ W,
                                                   const float* __restrict__ ST,
                                                   const int* __restrict__ kidx,
                                                   const int* __restrict__ fps,
                                                   const float* __restrict__ pos,
                                                   float* __restrict__ out)
{
    __shared__ float frow[KNN][DIN];
    const int p = blockIdx.x;
    const int o = threadIdx.x;
    const int b = p >> 12;
    const f4* featf = (const f4*)feat;
    f4* frow4 = (f4*)frow;
#pragma unroll
    for (int q = 0; q < 2; ++q) {
        int jj = o + q * 128;
        int row = jj >> 4, i4 = jj & 15;
        int id = kidx[p * KNN + row];
        frow4[jj] = featf[((size_t)b * Nc + id) * 16 + i4];
    }
    __syncthreads();
    float wreg[64];
#pragma unroll
    for (int i4 = 0; i4 < 16; ++i4) {
        f4 wv = ((const f4*)W)[o * 16 + i4];
        wreg[i4 * 4 + 0] = wv[0];
        wreg[i4 * 4 + 1] = wv[1];
        wreg[i4 * 4 + 2] = wv[2];
        wreg[i4 * 4 + 3] = wv[3];
    }
    const float s = ST[o], tt = ST[DOUT + o];
    float vm = 0.f;
    for (int k = 0; k < KNN; ++k) {
        float acc = 0.f;
#pragma unroll
        for (int i = 0; i < 64; ++i) acc = fmaf(frow[k][i], wreg[i], acc);
        vm = fmaxf(vm, fmaf(acc, s, tt));
    }
    out[POS_OUT + (size_t)p * DOUT + o] = vm;
    if (o < 3) {
        int id = fps[p];
        out[p * 3 + o] = pos[((size_t)b * Nc + id) * 3 + o];
    }
}

extern "C" void kernel_launch(void* const* d_in, const int* in_sizes, int n_in,
                              void* d_out, int out_size, void* d_ws, size_t ws_size,
                              hipStream_t stream)
{
    const float* pos   = (const float*)d_in[0];
    const float* feat  = (const float*)d_in[1];
    const int*   fps   = (const int*)d_in[2];
    const int*   kidx  = (const int*)d_in[3];
    const float* W     = (const float*)d_in[4];
    // d_in[5] = bias b: cancels exactly under BatchNorm, unused
    const float* gamma = (const float*)d_in[6];
    const float* beta  = (const float*)d_in[7];
    float* out = (float*)d_out;

    float* stats = (float*)d_ws;                 // [0,4160) colsum+gram
    float* ST = stats + PSTRIDE;                 // s,t (256 floats)
    const size_t F16_OFF = 32768;
    const size_t F16_BYTES = (size_t)Rr * DIN * 2;               // 32 MiB
    unsigned short* feat16 = (unsigned short*)((char*)d_ws + F16_OFF);
    float* part  = (float*)((char*)d_ws + F16_OFF + F16_BYTES);  // 17 MB partials
    float* part2 = part + (size_t)GBLK * PSTRIDE;                // 532 KB stage-2
    const size_t need = F16_OFF + F16_BYTES +
                        (size_t)(GBLK + RGRP) * PSTRIDE * 4;

    if (ws_size >= need) {
        k_gram<<<GBLK, 256, 0, stream>>>(feat, feat16, part);
        k_reduce1<<<dim3((PSTRIDE + 255) / 256, RGRP), 256, 0, stream>>>(part, part2);
        k_reduce2<<<(PSTRIDE + 255) / 256, 256, 0, stream>>>(part2, stats);
        k_stats<<<DOUT, 64, 0, stream>>>(stats, W, gamma, beta, ST);
        k_pos<<<(POS_OUT + 255) / 256, 256, 0, stream>>>(fps, pos, out);
        k_gmax<<<2048, 256, 0, stream>>>(feat16, W, ST, kidx, out);
    } else {
        hipMemsetAsync(d_ws, 0, PSTRIDE * 4, stream);
        k_gram_at<<<512, 256, 0, stream>>>(feat, stats);
        k_stats<<<DOUT, 64, 0, stream>>>(stats, W, gamma, beta, ST);
        k_gather_rc<<<Bc * Mc, 128, 0, stream>>>(feat, W, ST, kidx, fps, pos, out);
    }
}